// Round 1
// 26920.413 us; speedup vs baseline: 1.7161x; 1.7161x over previous
//
#include <hip/hip_runtime.h>
#include <cstdint>
#include <cstddef>

#define BB 1024
#define SS 100
#define HH 256
#define CH 512   // batch chunk rows (2 chunks)

// ---------------------------------------------------------------------------
// Bit-exact JAX threefry2x32 (partitionable mode — verified round 3)
// ---------------------------------------------------------------------------
__device__ __forceinline__ unsigned rotl32(unsigned v, int r) {
  return (v << r) | (v >> (32 - r));
}

__device__ __forceinline__ void threefry2x32(unsigned k0, unsigned k1,
                                             unsigned x0, unsigned x1,
                                             unsigned& o0, unsigned& o1) {
  unsigned k2 = k0 ^ k1 ^ 0x1BD11BDAu;
  x0 += k0; x1 += k1;
#define TF_R(r) { x0 += x1; x1 = rotl32(x1, (r)); x1 ^= x0; }
  TF_R(13) TF_R(15) TF_R(26) TF_R(6)
  x0 += k1; x1 += k2 + 1u;
  TF_R(17) TF_R(29) TF_R(16) TF_R(24)
  x0 += k2; x1 += k0 + 2u;
  TF_R(13) TF_R(15) TF_R(26) TF_R(6)
  x0 += k0; x1 += k1 + 3u;
  TF_R(17) TF_R(29) TF_R(16) TF_R(24)
  x0 += k1; x1 += k2 + 4u;
  TF_R(13) TF_R(15) TF_R(26) TF_R(6)
  x0 += k2; x1 += k0 + 5u;
#undef TF_R
  o0 = x0; o1 = x1;
}

__device__ __forceinline__ double sigd(double x) {
  return 1.0 / (1.0 + exp(-x));
}

// Fast fp32 tanh: 1 - 2/(e^{2x}+1). v_exp_f32 + v_rcp_f32, ~6 instrs.
// abs err ~2e-7; correct saturation at +/-inf (exp->inf => 1, exp->0 => -1).
__device__ __forceinline__ float tanh_fast(float x) {
  float e = __expf(2.0f * x);
  return 1.0f - 2.0f * __builtin_amdgcn_rcpf(e + 1.0f);
}

// ---------------------------------------------------------------------------
__global__ __launch_bounds__(256) void init_chunk(
    double* __restrict__ h, double* __restrict__ c) {
  int i = blockIdx.x * 256 + threadIdx.x;
  h[i] = 0.0;
  c[i] = 0.0;
}

__global__ __launch_bounds__(256) void init_dec(
    double* __restrict__ dec_in, int* __restrict__ mask,
    const float* __restrict__ start) {
  int r = blockIdx.x, t = threadIdx.x;
  dec_in[r * HH + t] = (double)start[t];
  if (t < SS) mask[r * SS + t] = 0;
}

// WqT[k,t] = Wq[t,k] for the two 256x256 query-projection matrices
__global__ __launch_bounds__(256) void transpose2(
    const float* __restrict__ a, const float* __restrict__ b,
    float* __restrict__ at, float* __restrict__ bt) {
  int k = blockIdx.x, t = threadIdx.x;
  at[k * HH + t] = a[t * HH + k];
  bt[k * HH + t] = b[t * HH + k];
}

// ---------------------------------------------------------------------------
// Fused LSTM step: gates = A@Wih^T + bih + h@Whh^T + bhh ; LSTM nonlinearity
// in-register; writes h,c (and optional enc_c fp32 slice).
// A = embed(inputs[:,t,:]) computed on the fly (EMBED) or dec_in (fp64).
// Tile: 32 rows x 16 u-cols x 4 gates. Thread: 2 rows x 4 gates of one u.
// Grid: (CH/32, 16). All math fp64.
// ---------------------------------------------------------------------------
template <bool EMBED>
__global__ __launch_bounds__(256) void lstm_gates(
    const float* __restrict__ inputs, const float* __restrict__ emb_w,
    const float* __restrict__ emb_b, int t, int cb,
    const double* __restrict__ dec_in,
    const float* __restrict__ Wih, const float* __restrict__ Whh,
    const float* __restrict__ bih, const float* __restrict__ bhh,
    double* __restrict__ h, double* __restrict__ c,
    float* __restrict__ enc_c) {
  __shared__ double As[16][34];
  __shared__ double Ws[16][66];
  const int tid = threadIdx.x;
  const int tx = tid & 15;          // u within block
  const int ty = tid >> 4;          // row pair
  const int m0 = blockIdx.x * 32;
  const int u0 = blockIdx.y * 16;
  // staging roles
  const int arow = tid >> 3;              // 0..31
  const int acol = (tid & 7) * 2;         // 0,2,..,14
  const int wn   = tid >> 2;              // 0..63  (n_local = gate*16+u_loc)
  const int wcol = (tid & 3) * 4;         // 0,4,8,12
  const int wgate = wn >> 4, wu = wn & 15;
  double acc[2][4] = {};

  // hoisted embed inputs for this thread's staging row
  double in0 = 0.0, in1 = 0.0;
  if (EMBED) {
    int b = cb + m0 + arow;
    in0 = (double)inputs[(b * SS + t) * 2];
    in1 = (double)inputs[(b * SS + t) * 2 + 1];
  }

  for (int ph = 0; ph < 2; ++ph) {
    const float* W = ph ? Whh : Wih;
    const float* wrow = W + (size_t)(wgate * HH + u0 + wu) * HH;
    for (int k0 = 0; k0 < HH; k0 += 16) {
      double a0, a1;
      if (ph == 0) {
        if (EMBED) {
          int k = k0 + acol;
          a0 = in0 * (double)emb_w[2 * k] + in1 * (double)emb_w[2 * k + 1] +
               (double)emb_b[k];
          a1 = in0 * (double)emb_w[2 * k + 2] + in1 * (double)emb_w[2 * k + 3] +
               (double)emb_b[k + 1];
        } else {
          const double* ar = dec_in + (size_t)(m0 + arow) * HH + k0 + acol;
          a0 = ar[0]; a1 = ar[1];
        }
      } else {
        const double* ar = h + (size_t)(m0 + arow) * HH + k0 + acol;
        a0 = ar[0]; a1 = ar[1];
      }
      float4 wv = *(const float4*)(wrow + k0 + wcol);
      __syncthreads();
      As[acol][arow] = a0;
      As[acol + 1][arow] = a1;
      Ws[wcol + 0][wn] = (double)wv.x;
      Ws[wcol + 1][wn] = (double)wv.y;
      Ws[wcol + 2][wn] = (double)wv.z;
      Ws[wcol + 3][wn] = (double)wv.w;
      __syncthreads();
#pragma unroll
      for (int kk = 0; kk < 16; ++kk) {
        double a0k = As[kk][ty * 2];
        double a1k = As[kk][ty * 2 + 1];
#pragma unroll
        for (int j = 0; j < 4; ++j) {
          double w = Ws[kk][j * 16 + tx];
          acc[0][j] = fma(a0k, w, acc[0][j]);
          acc[1][j] = fma(a1k, w, acc[1][j]);
        }
      }
    }
  }

  const int u = u0 + tx;
#pragma unroll
  for (int i = 0; i < 2; ++i) {
    int r = m0 + ty * 2 + i;
    double gi = acc[i][0] + (double)bih[u] + (double)bhh[u];
    double gf = acc[i][1] + (double)bih[HH + u] + (double)bhh[HH + u];
    double gg = acc[i][2] + (double)bih[2 * HH + u] + (double)bhh[2 * HH + u];
    double go = acc[i][3] + (double)bih[3 * HH + u] + (double)bhh[3 * HH + u];
    size_t idx = (size_t)r * HH + u;
    double cp = c[idx];
    double cn = sigd(gf) * cp + sigd(gi) * tanh(gg);
    double hn = sigd(go) * tanh(cn);
    c[idx] = cn;
    h[idx] = hn;
    if (enc_c) enc_c[((size_t)r * SS + t) * HH + u] = (float)hn;
  }
}

// ---------------------------------------------------------------------------
// Ref projection: C[m,n] = sum_k A[m,k]*W[n,k] + b[n]; A,C fp32, math fp64.
// Tile 64x64, thread 4x4, K=256.
// ---------------------------------------------------------------------------
__global__ __launch_bounds__(256) void proj_gemm(
    const float* __restrict__ A, const float* __restrict__ W,
    const float* __restrict__ bias, float* __restrict__ C) {
  __shared__ double As[16][68];
  __shared__ double Ws[16][68];
  const int tid = threadIdx.x;
  const int tx = tid & 15, ty = tid >> 4;
  const int m0 = blockIdx.x * 64;
  const int n0 = blockIdx.y * 64;
  const int lrow = tid >> 2;
  const int lcol = (tid & 3) << 2;
  double acc[4][4] = {};

  const float* ar = A + (size_t)(m0 + lrow) * HH;
  const float* wr = W + (size_t)(n0 + lrow) * HH;
  for (int k0 = 0; k0 < HH; k0 += 16) {
    float4 av = *(const float4*)(ar + k0 + lcol);
    float4 wv = *(const float4*)(wr + k0 + lcol);
    __syncthreads();
    As[lcol + 0][lrow] = (double)av.x; As[lcol + 1][lrow] = (double)av.y;
    As[lcol + 2][lrow] = (double)av.z; As[lcol + 3][lrow] = (double)av.w;
    Ws[lcol + 0][lrow] = (double)wv.x; Ws[lcol + 1][lrow] = (double)wv.y;
    Ws[lcol + 2][lrow] = (double)wv.z; Ws[lcol + 3][lrow] = (double)wv.w;
    __syncthreads();
#pragma unroll
    for (int kk = 0; kk < 16; ++kk) {
      double a[4], w[4];
#pragma unroll
      for (int i = 0; i < 4; ++i) a[i] = As[kk][ty * 4 + i];
#pragma unroll
      for (int j = 0; j < 4; ++j) w[j] = Ws[kk][tx * 4 + j];
#pragma unroll
      for (int i = 0; i < 4; ++i)
#pragma unroll
        for (int j = 0; j < 4; ++j) acc[i][j] = fma(a[i], w[j], acc[i][j]);
    }
  }
#pragma unroll
  for (int i = 0; i < 4; ++i) {
    float* crow = C + (size_t)(m0 + ty * 4 + i) * HH + n0 + tx * 4;
#pragma unroll
    for (int j = 0; j < 4; ++j)
      crow[j] = (float)(acc[i][j] + (double)bias[n0 + tx * 4 + j]);
  }
}

// ---------------------------------------------------------------------------
// Fused decoder attention + sampling, one block per batch row r.
//   qg = h@Wq_g^T + b; gl[s] = attn(ref_g, qg); wgt = softmax(gl);
//   q  = sum_s enc[s]*wgt[s]; qp = q@Wq_p^T + b; pl[s] = attn(ref_p, qp);
//   gumbel-argmax sample; lps/chs outputs; mask, dec_in update.
// Logits tanh-path in fast fp32 (err ~1e-6 on logits — far below the ~1.5e-2
// fp32-reference noise floor); softmax / gumbel / log-softmax stay fp64
// (gumbel argmax gap sensitivity). Wq pre-transposed for coalescing.
// ---------------------------------------------------------------------------
__global__ __launch_bounds__(256) void dec_attn_sample(
    const double* __restrict__ h,
    const float* __restrict__ enc_c, const float* __restrict__ ref_g,
    const float* __restrict__ ref_p,
    const float* __restrict__ wqt_g, const float* __restrict__ bq_g,
    const float* __restrict__ vw_g, const float* __restrict__ vb_g,
    const float* __restrict__ wqt_p, const float* __restrict__ bq_p,
    const float* __restrict__ vw_p, const float* __restrict__ vb_p,
    int* __restrict__ mask, double* __restrict__ dec_in,
    const float* __restrict__ inputs, const float* __restrict__ emb_w,
    const float* __restrict__ emb_b,
    float* __restrict__ out, int step, int cb) {
  __shared__ double hq[HH];                 // h row, then glimpse q row
  __shared__ __align__(16) float qvf[HH];   // projected query (fp32)
  __shared__ double lg[SS];                 // logits, then softmax weights
  __shared__ double red[256];
  __shared__ int    ridx[256];
  __shared__ int    sh_chosen;

  const int r = blockIdx.x, t = threadIdx.x;
  const int w = t >> 6, l = t & 63;
  const int b = cb + r;

  hq[t] = h[(size_t)r * HH + t];
  __syncthreads();

  // ---- glimpse query projection (fp64 accum, 4-way ILP) ----
  {
    double a0 = 0.0, a1 = 0.0, a2 = 0.0, a3 = 0.0;
    for (int k = 0; k < HH; k += 4) {
      a0 = fma((double)wqt_g[(k + 0) * HH + t], hq[k + 0], a0);
      a1 = fma((double)wqt_g[(k + 1) * HH + t], hq[k + 1], a1);
      a2 = fma((double)wqt_g[(k + 2) * HH + t], hq[k + 2], a2);
      a3 = fma((double)wqt_g[(k + 3) * HH + t], hq[k + 3], a3);
    }
    qvf[t] = (float)(((a0 + a1) + (a2 + a3)) + (double)bq_g[t]);
  }
  __syncthreads();

  // ---- glimpse logits (fast fp32 tanh path) ----
  {
    const float4 vg = *(const float4*)(vw_g + l * 4);
    const float4 qf = *(const float4*)(qvf + l * 4);
    const float vb = vb_g[0];
    for (int s = w; s < SS; s += 4) {
      if (mask[r * SS + s]) {
        if (l == 0) lg[s] = -10.0;
        continue;
      }
      const float4 rp = *(const float4*)(ref_g + ((size_t)r * SS + s) * HH + l * 4);
      float p = tanh_fast(rp.x + qf.x) * vg.x;
      p = fmaf(tanh_fast(rp.y + qf.y), vg.y, p);
      p = fmaf(tanh_fast(rp.z + qf.z), vg.z, p);
      p = fmaf(tanh_fast(rp.w + qf.w), vg.w, p);
#pragma unroll
      for (int off = 32; off; off >>= 1) p += __shfl_xor(p, off);
      float z = 10.0f * tanh_fast(p + vb);
      if (l == 0) lg[s] = (double)z;
    }
  }
  __syncthreads();

  // ---- softmax over gl -> weights in lg (fp64) ----
  {
    double x = (t < SS) ? lg[t] : -1e300;
    red[t] = x;
    __syncthreads();
    for (int st = 128; st; st >>= 1) {
      if (t < st) red[t] = fmax(red[t], red[t + st]);
      __syncthreads();
    }
    double mx = red[0];
    __syncthreads();
    double e = (t < SS) ? exp(x - mx) : 0.0;
    red[t] = e;
    __syncthreads();
    for (int st = 128; st; st >>= 1) {
      if (t < st) red[t] += red[t + st];
      __syncthreads();
    }
    double sum = red[0];
    __syncthreads();
    if (t < SS) lg[t] = e / sum;
  }
  __syncthreads();

  // ---- weighted sum of enc -> glimpse q (into hq), 2-way ILP ----
  {
    const float* eb = enc_c + (size_t)r * SS * HH + t;
    double acc0 = 0.0, acc1 = 0.0;
    for (int s = 0; s < SS; s += 2) {
      acc0 = fma((double)eb[(s + 0) * HH], lg[s + 0], acc0);
      acc1 = fma((double)eb[(s + 1) * HH], lg[s + 1], acc1);
    }
    __syncthreads();
    hq[t] = acc0 + acc1;
  }
  __syncthreads();

  // ---- pointer query projection (fp64 accum, 4-way ILP) ----
  {
    double a0 = 0.0, a1 = 0.0, a2 = 0.0, a3 = 0.0;
    for (int k = 0; k < HH; k += 4) {
      a0 = fma((double)wqt_p[(k + 0) * HH + t], hq[k + 0], a0);
      a1 = fma((double)wqt_p[(k + 1) * HH + t], hq[k + 1], a1);
      a2 = fma((double)wqt_p[(k + 2) * HH + t], hq[k + 2], a2);
      a3 = fma((double)wqt_p[(k + 3) * HH + t], hq[k + 3], a3);
    }
    qvf[t] = (float)(((a0 + a1) + (a2 + a3)) + (double)bq_p[t]);
  }
  __syncthreads();

  // ---- pointer logits (fast fp32 tanh path) ----
  {
    const float4 vg = *(const float4*)(vw_p + l * 4);
    const float4 qf = *(const float4*)(qvf + l * 4);
    const float vb = vb_p[0];
    for (int s = w; s < SS; s += 4) {
      if (mask[r * SS + s]) {
        if (l == 0) lg[s] = -10.0;
        continue;
      }
      const float4 rp = *(const float4*)(ref_p + ((size_t)r * SS + s) * HH + l * 4);
      float p = tanh_fast(rp.x + qf.x) * vg.x;
      p = fmaf(tanh_fast(rp.y + qf.y), vg.y, p);
      p = fmaf(tanh_fast(rp.z + qf.z), vg.z, p);
      p = fmaf(tanh_fast(rp.w + qf.w), vg.w, p);
#pragma unroll
      for (int off = 32; off; off >>= 1) p += __shfl_xor(p, off);
      float z = 10.0f * tanh_fast(p + vb);
      if (l == 0) lg[s] = (double)z;
    }
  }
  __syncthreads();

  // ---- gumbel-argmax (partitionable threefry, exact round-3 recipe) ----
  // Kept in fp64: gumbel top-2 gaps can be ~1e-5; fp32 here risks flips.
  double x = (t < SS) ? lg[t] : -1e300;
  double val = -1e300;
  if (t < SS) {
    unsigned kk0, kk1;
    threefry2x32(0u, 42u, 0u, (unsigned)step, kk0, kk1);
    unsigned j = (unsigned)(b * SS + t);
    unsigned o0, o1;
    threefry2x32(kk0, kk1, 0u, j, o0, o1);
    unsigned bits = o0 ^ o1;
    double u = (double)(bits >> 9) * 0x1p-23;
    if (u == 0.0) u = 1.17549435e-38;
    val = x + (-log(-log(u)));
  }
  red[t] = val;
  ridx[t] = t;
  __syncthreads();
  for (int st = 128; st; st >>= 1) {
    if (t < st) {
      double v1 = red[t], v2 = red[t + st];
      int i1 = ridx[t], i2 = ridx[t + st];
      if (v2 > v1 || (v2 == v1 && i2 < i1)) { red[t] = v2; ridx[t] = i2; }
    }
    __syncthreads();
  }
  if (t == 0) sh_chosen = ridx[0];
  __syncthreads();
  int chosen = sh_chosen;

  // ---- log-softmax pieces (fp64) ----
  red[t] = x;
  __syncthreads();
  for (int st = 128; st; st >>= 1) {
    if (t < st) red[t] = fmax(red[t], red[t + st]);
    __syncthreads();
  }
  double mx = red[0];
  __syncthreads();
  red[t] = (t < SS) ? exp(x - mx) : 0.0;
  __syncthreads();
  for (int st = 128; st; st >>= 1) {
    if (t < st) red[t] += red[t + st];
    __syncthreads();
  }
  if (t == 0) {
    double lse = log(red[0]);
    double xc = lg[chosen];
    out[(size_t)b * SS + step] = (float)(xc - mx - lse);            // lps
    out[(size_t)BB * SS + (size_t)b * SS + step] = (float)chosen;   // chs
    mask[r * SS + chosen] = 1;
  }
  __syncthreads();

  // ---- dec_in = embedded[b, chosen, :] (fp64 recompute) ----
  int ib = (b * SS + chosen) * 2;
  double i0 = (double)inputs[ib], i1 = (double)inputs[ib + 1];
  dec_in[(size_t)r * HH + t] =
      i0 * (double)emb_w[2 * t] + i1 * (double)emb_w[2 * t + 1] + (double)emb_b[t];
}

// Diagnostic: encode ws_size (MB) into output so absmax reveals it.
__global__ __launch_bounds__(256) void diag_kernel(float* __restrict__ out, float v) {
  int i = blockIdx.x * 256 + threadIdx.x;
  if (i < 2 * BB * SS) out[i] = v;
}

// ---------------------------------------------------------------------------
extern "C" void kernel_launch(void* const* d_in, const int* in_sizes, int n_in,
                              void* d_out, int out_size, void* d_ws, size_t ws_size,
                              hipStream_t stream) {
  (void)in_sizes; (void)n_in; (void)out_size;
  const float* inputs    = (const float*)d_in[0];
  const float* emb_w     = (const float*)d_in[1];
  const float* emb_b     = (const float*)d_in[2];
  const float* enc_wih   = (const float*)d_in[3];
  const float* enc_whh   = (const float*)d_in[4];
  const float* enc_bih   = (const float*)d_in[5];
  const float* enc_bhh   = (const float*)d_in[6];
  const float* dec_wih   = (const float*)d_in[7];
  const float* dec_whh   = (const float*)d_in[8];
  const float* dec_bih   = (const float*)d_in[9];
  const float* dec_bhh   = (const float*)d_in[10];
  const float* ptr_wq_w  = (const float*)d_in[11];
  const float* ptr_wq_b  = (const float*)d_in[12];
  const float* ptr_wref_w= (const float*)d_in[13];
  const float* ptr_wref_b= (const float*)d_in[14];
  const float* ptr_v_w   = (const float*)d_in[15];
  const float* ptr_v_b   = (const float*)d_in[16];
  const float* glm_wq_w  = (const float*)d_in[17];
  const float* glm_wq_b  = (const float*)d_in[18];
  const float* glm_wref_w= (const float*)d_in[19];
  const float* glm_wref_b= (const float*)d_in[20];
  const float* glm_v_w   = (const float*)d_in[21];
  const float* glm_v_b   = (const float*)d_in[22];
  const float* start     = (const float*)d_in[23];
  float* out = (float*)d_out;

  char* base_p = (char*)d_ws;
  size_t off = 0;
  auto take = [&](size_t nbytes) {
    void* p = base_p + off;
    off = (off + nbytes + 255) & ~(size_t)255;
    return p;
  };
  const size_t BIGC = (size_t)CH * SS * HH;           // 13,107,200 elems
  float*  enc_c  = (float*)take(BIGC * 4);            // 52.4 MB
  float*  ref_g  = (float*)take(BIGC * 4);            // 52.4 MB
  float*  ref_p  = (float*)take(BIGC * 4);            // 52.4 MB
  double* hbuf   = (double*)take((size_t)CH * HH * 8);
  double* cbuf   = (double*)take((size_t)CH * HH * 8);
  double* dec_in = (double*)take((size_t)CH * HH * 8);
  int*    mask   = (int*)take((size_t)CH * SS * 4);
  float*  wqt_g  = (float*)take((size_t)HH * HH * 4);
  float*  wqt_p  = (float*)take((size_t)HH * HH * 4);

  if (ws_size < off) {
    diag_kernel<<<(2 * BB * SS + 255) / 256, 256, 0, stream>>>(
        out, (float)(ws_size >> 20));
    return;
  }

  transpose2<<<HH, HH, 0, stream>>>(glm_wq_w, ptr_wq_w, wqt_g, wqt_p);

  for (int cb = 0; cb < BB; cb += CH) {
    // ---- encoder ----
    init_chunk<<<CH, 256, 0, stream>>>(hbuf, cbuf);
    for (int t = 0; t < SS; ++t) {
      lstm_gates<true><<<dim3(CH / 32, 16), 256, 0, stream>>>(
          inputs, emb_w, emb_b, t, cb, nullptr,
          enc_wih, enc_whh, enc_bih, enc_bhh, hbuf, cbuf, enc_c);
    }

    // ---- ref projections (CH*SS rows) ----
    proj_gemm<<<dim3(CH * SS / 64, 4), 256, 0, stream>>>(
        enc_c, glm_wref_w, glm_wref_b, ref_g);
    proj_gemm<<<dim3(CH * SS / 64, 4), 256, 0, stream>>>(
        enc_c, ptr_wref_w, ptr_wref_b, ref_p);

    // ---- decoder ----
    init_dec<<<CH, 256, 0, stream>>>(dec_in, mask, start);
    for (int k = 0; k < SS; ++k) {
      lstm_gates<false><<<dim3(CH / 32, 16), 256, 0, stream>>>(
          inputs, emb_w, emb_b, 0, cb, dec_in,
          dec_wih, dec_whh, dec_bih, dec_bhh, hbuf, cbuf, nullptr);
      dec_attn_sample<<<CH, 256, 0, stream>>>(
          hbuf, enc_c, ref_g, ref_p,
          wqt_g, glm_wq_b, glm_v_w, glm_v_b,
          wqt_p, ptr_wq_b, ptr_v_w, ptr_v_b,
          mask, dec_in, inputs, emb_w, emb_b, out, k, cb);
    }
  }
}

// Round 2
// 26500.998 us; speedup vs baseline: 1.7433x; 1.0158x over previous
//
#include <hip/hip_runtime.h>
#include <cstdint>
#include <cstddef>

#define BB 1024
#define SS 100
#define HH 256

// ---------------------------------------------------------------------------
// Bit-exact JAX threefry2x32 (partitionable mode — verified round 3)
// ---------------------------------------------------------------------------
__device__ __forceinline__ unsigned rotl32(unsigned v, int r) {
  return (v << r) | (v >> (32 - r));
}

__device__ __forceinline__ void threefry2x32(unsigned k0, unsigned k1,
                                             unsigned x0, unsigned x1,
                                             unsigned& o0, unsigned& o1) {
  unsigned k2 = k0 ^ k1 ^ 0x1BD11BDAu;
  x0 += k0; x1 += k1;
#define TF_R(r) { x0 += x1; x1 = rotl32(x1, (r)); x1 ^= x0; }
  TF_R(13) TF_R(15) TF_R(26) TF_R(6)
  x0 += k1; x1 += k2 + 1u;
  TF_R(17) TF_R(29) TF_R(16) TF_R(24)
  x0 += k2; x1 += k0 + 2u;
  TF_R(13) TF_R(15) TF_R(26) TF_R(6)
  x0 += k0; x1 += k1 + 3u;
  TF_R(17) TF_R(29) TF_R(16) TF_R(24)
  x0 += k1; x1 += k2 + 4u;
  TF_R(13) TF_R(15) TF_R(26) TF_R(6)
  x0 += k2; x1 += k0 + 5u;
#undef TF_R
  o0 = x0; o1 = x1;
}

__device__ __forceinline__ double sigd(double x) {
  return 1.0 / (1.0 + exp(-x));
}

// Fast fp32 tanh: 1 - 2/(e^{2x}+1). v_exp_f32 + v_rcp_f32, ~6 instrs.
// abs err ~2e-7; correct saturation at +/-inf.
__device__ __forceinline__ float tanh_fast(float x) {
  float e = __expf(2.0f * x);
  return 1.0f - 2.0f * __builtin_amdgcn_rcpf(e + 1.0f);
}

// wave-level (64-lane) reductions via shuffle — no barriers
__device__ __forceinline__ double wave_max(double v) {
#pragma unroll
  for (int off = 32; off; off >>= 1) v = fmax(v, __shfl_xor(v, off));
  return v;
}
__device__ __forceinline__ double wave_sum(double v) {
#pragma unroll
  for (int off = 32; off; off >>= 1) v += __shfl_xor(v, off);
  return v;
}

// ---------------------------------------------------------------------------
__global__ __launch_bounds__(256) void init_chunk(
    double* __restrict__ h, double* __restrict__ c) {
  int i = blockIdx.x * 256 + threadIdx.x;
  h[i] = 0.0;
  c[i] = 0.0;
}

__global__ __launch_bounds__(256) void init_dec(
    double* __restrict__ dec_in, int* __restrict__ mask,
    const float* __restrict__ start) {
  int r = blockIdx.x, t = threadIdx.x;
  dec_in[r * HH + t] = (double)start[t];
  if (t < SS) mask[r * SS + t] = 0;
}

// WqT[k,t] = Wq[t,k] for the two 256x256 query-projection matrices
__global__ __launch_bounds__(256) void transpose2(
    const float* __restrict__ a, const float* __restrict__ b,
    float* __restrict__ at, float* __restrict__ bt) {
  int k = blockIdx.x, t = threadIdx.x;
  at[k * HH + t] = a[t * HH + k];
  bt[k * HH + t] = b[t * HH + k];
}

// ---------------------------------------------------------------------------
// Fused LSTM step: gates = A@Wih^T + bih + h@Whh^T + bhh ; LSTM nonlinearity
// in-register; writes h,c (and optional enc_c fp32 slice).
// A = embed(inputs[:,t,:]) computed on the fly (EMBED) or dec_in (fp64).
// Tile: 32 rows x 16 u-cols x 4 gates. Thread: 2 rows x 4 gates of one u.
// Grid: (chunk/32, 16). All math fp64.
// ---------------------------------------------------------------------------
template <bool EMBED>
__global__ __launch_bounds__(256) void lstm_gates(
    const float* __restrict__ inputs, const float* __restrict__ emb_w,
    const float* __restrict__ emb_b, int t, int cb,
    const double* __restrict__ dec_in,
    const float* __restrict__ Wih, const float* __restrict__ Whh,
    const float* __restrict__ bih, const float* __restrict__ bhh,
    double* __restrict__ h, double* __restrict__ c,
    float* __restrict__ enc_c) {
  __shared__ double As[16][34];
  __shared__ double Ws[16][66];
  const int tid = threadIdx.x;
  const int tx = tid & 15;          // u within block
  const int ty = tid >> 4;          // row pair
  const int m0 = blockIdx.x * 32;
  const int u0 = blockIdx.y * 16;
  // staging roles
  const int arow = tid >> 3;              // 0..31
  const int acol = (tid & 7) * 2;         // 0,2,..,14
  const int wn   = tid >> 2;              // 0..63  (n_local = gate*16+u_loc)
  const int wcol = (tid & 3) * 4;         // 0,4,8,12
  const int wgate = wn >> 4, wu = wn & 15;
  double acc[2][4] = {};

  // hoisted embed inputs for this thread's staging row
  double in0 = 0.0, in1 = 0.0;
  if (EMBED) {
    int b = cb + m0 + arow;
    in0 = (double)inputs[(b * SS + t) * 2];
    in1 = (double)inputs[(b * SS + t) * 2 + 1];
  }

  for (int ph = 0; ph < 2; ++ph) {
    const float* W = ph ? Whh : Wih;
    const float* wrow = W + (size_t)(wgate * HH + u0 + wu) * HH;
    for (int k0 = 0; k0 < HH; k0 += 16) {
      double a0, a1;
      if (ph == 0) {
        if (EMBED) {
          int k = k0 + acol;
          a0 = in0 * (double)emb_w[2 * k] + in1 * (double)emb_w[2 * k + 1] +
               (double)emb_b[k];
          a1 = in0 * (double)emb_w[2 * k + 2] + in1 * (double)emb_w[2 * k + 3] +
               (double)emb_b[k + 1];
        } else {
          const double* ar = dec_in + (size_t)(m0 + arow) * HH + k0 + acol;
          a0 = ar[0]; a1 = ar[1];
        }
      } else {
        const double* ar = h + (size_t)(m0 + arow) * HH + k0 + acol;
        a0 = ar[0]; a1 = ar[1];
      }
      float4 wv = *(const float4*)(wrow + k0 + wcol);
      __syncthreads();
      As[acol][arow] = a0;
      As[acol + 1][arow] = a1;
      Ws[wcol + 0][wn] = (double)wv.x;
      Ws[wcol + 1][wn] = (double)wv.y;
      Ws[wcol + 2][wn] = (double)wv.z;
      Ws[wcol + 3][wn] = (double)wv.w;
      __syncthreads();
#pragma unroll
      for (int kk = 0; kk < 16; ++kk) {
        double a0k = As[kk][ty * 2];
        double a1k = As[kk][ty * 2 + 1];
#pragma unroll
        for (int j = 0; j < 4; ++j) {
          double w = Ws[kk][j * 16 + tx];
          acc[0][j] = fma(a0k, w, acc[0][j]);
          acc[1][j] = fma(a1k, w, acc[1][j]);
        }
      }
    }
  }

  const int u = u0 + tx;
#pragma unroll
  for (int i = 0; i < 2; ++i) {
    int r = m0 + ty * 2 + i;
    double gi = acc[i][0] + (double)bih[u] + (double)bhh[u];
    double gf = acc[i][1] + (double)bih[HH + u] + (double)bhh[HH + u];
    double gg = acc[i][2] + (double)bih[2 * HH + u] + (double)bhh[2 * HH + u];
    double go = acc[i][3] + (double)bih[3 * HH + u] + (double)bhh[3 * HH + u];
    size_t idx = (size_t)r * HH + u;
    double cp = c[idx];
    double cn = sigd(gf) * cp + sigd(gi) * tanh(gg);
    double hn = sigd(go) * tanh(cn);
    c[idx] = cn;
    h[idx] = hn;
    if (enc_c) enc_c[((size_t)r * SS + t) * HH + u] = (float)hn;
  }
}

// ---------------------------------------------------------------------------
// Ref projection: C[m,n] = sum_k A[m,k]*W[n,k] + b[n]; A,C fp32, math fp64.
// Tile 64x64, thread 4x4, K=256.
// ---------------------------------------------------------------------------
__global__ __launch_bounds__(256) void proj_gemm(
    const float* __restrict__ A, const float* __restrict__ W,
    const float* __restrict__ bias, float* __restrict__ C) {
  __shared__ double As[16][68];
  __shared__ double Ws[16][68];
  const int tid = threadIdx.x;
  const int tx = tid & 15, ty = tid >> 4;
  const int m0 = blockIdx.x * 64;
  const int n0 = blockIdx.y * 64;
  const int lrow = tid >> 2;
  const int lcol = (tid & 3) << 2;
  double acc[4][4] = {};

  const float* ar = A + (size_t)(m0 + lrow) * HH;
  const float* wr = W + (size_t)(n0 + lrow) * HH;
  for (int k0 = 0; k0 < HH; k0 += 16) {
    float4 av = *(const float4*)(ar + k0 + lcol);
    float4 wv = *(const float4*)(wr + k0 + lcol);
    __syncthreads();
    As[lcol + 0][lrow] = (double)av.x; As[lcol + 1][lrow] = (double)av.y;
    As[lcol + 2][lrow] = (double)av.z; As[lcol + 3][lrow] = (double)av.w;
    Ws[lcol + 0][lrow] = (double)wv.x; Ws[lcol + 1][lrow] = (double)wv.y;
    Ws[lcol + 2][lrow] = (double)wv.z; Ws[lcol + 3][lrow] = (double)wv.w;
    __syncthreads();
#pragma unroll
    for (int kk = 0; kk < 16; ++kk) {
      double a[4], w[4];
#pragma unroll
      for (int i = 0; i < 4; ++i) a[i] = As[kk][ty * 4 + i];
#pragma unroll
      for (int j = 0; j < 4; ++j) w[j] = Ws[kk][tx * 4 + j];
#pragma unroll
      for (int i = 0; i < 4; ++i)
#pragma unroll
        for (int j = 0; j < 4; ++j) acc[i][j] = fma(a[i], w[j], acc[i][j]);
    }
  }
#pragma unroll
  for (int i = 0; i < 4; ++i) {
    float* crow = C + (size_t)(m0 + ty * 4 + i) * HH + n0 + tx * 4;
#pragma unroll
    for (int j = 0; j < 4; ++j)
      crow[j] = (float)(acc[i][j] + (double)bias[n0 + tx * 4 + j]);
  }
}

// ---------------------------------------------------------------------------
// Fused decoder attention + sampling, one block per batch row r.
// Logits tanh-path in fast fp32; softmax / gumbel / log-softmax fp64.
// Block reductions = wave shuffle (6 steps) + 4-element LDS combine:
// ~16 barriers/block instead of ~45.
// ---------------------------------------------------------------------------
__global__ __launch_bounds__(256) void dec_attn_sample(
    const double* __restrict__ h,
    const float* __restrict__ enc_c, const float* __restrict__ ref_g,
    const float* __restrict__ ref_p,
    const float* __restrict__ wqt_g, const float* __restrict__ bq_g,
    const float* __restrict__ vw_g, const float* __restrict__ vb_g,
    const float* __restrict__ wqt_p, const float* __restrict__ bq_p,
    const float* __restrict__ vw_p, const float* __restrict__ vb_p,
    int* __restrict__ mask, double* __restrict__ dec_in,
    const float* __restrict__ inputs, const float* __restrict__ emb_w,
    const float* __restrict__ emb_b,
    float* __restrict__ out, int step, int cb) {
  __shared__ double hq[HH];                 // h row, then glimpse q row
  __shared__ __align__(16) float qvf[HH];   // projected query (fp32)
  __shared__ double lg[SS];                 // logits, then softmax weights
  __shared__ double redw[4];
  __shared__ int    ridxw[4];
  __shared__ int    sh_chosen;

  const int r = blockIdx.x, t = threadIdx.x;
  const int w = t >> 6, l = t & 63;
  const int b = cb + r;

  hq[t] = h[(size_t)r * HH + t];
  __syncthreads();

  // ---- glimpse query projection (fp64 accum, 4-way ILP) ----
  {
    double a0 = 0.0, a1 = 0.0, a2 = 0.0, a3 = 0.0;
    for (int k = 0; k < HH; k += 4) {
      a0 = fma((double)wqt_g[(k + 0) * HH + t], hq[k + 0], a0);
      a1 = fma((double)wqt_g[(k + 1) * HH + t], hq[k + 1], a1);
      a2 = fma((double)wqt_g[(k + 2) * HH + t], hq[k + 2], a2);
      a3 = fma((double)wqt_g[(k + 3) * HH + t], hq[k + 3], a3);
    }
    qvf[t] = (float)(((a0 + a1) + (a2 + a3)) + (double)bq_g[t]);
  }
  __syncthreads();

  // ---- glimpse logits (fast fp32 tanh path) ----
  {
    const float4 vg = *(const float4*)(vw_g + l * 4);
    const float4 qf = *(const float4*)(qvf + l * 4);
    const float vb = vb_g[0];
    for (int s = w; s < SS; s += 4) {
      if (mask[r * SS + s]) {
        if (l == 0) lg[s] = -10.0;
        continue;
      }
      const float4 rp = *(const float4*)(ref_g + ((size_t)r * SS + s) * HH + l * 4);
      float p = tanh_fast(rp.x + qf.x) * vg.x;
      p = fmaf(tanh_fast(rp.y + qf.y), vg.y, p);
      p = fmaf(tanh_fast(rp.z + qf.z), vg.z, p);
      p = fmaf(tanh_fast(rp.w + qf.w), vg.w, p);
#pragma unroll
      for (int off = 32; off; off >>= 1) p += __shfl_xor(p, off);
      float z = 10.0f * tanh_fast(p + vb);
      if (l == 0) lg[s] = (double)z;
    }
  }
  __syncthreads();

  // ---- softmax over gl -> weights in lg (fp64, wave reduce) ----
  {
    double x = (t < SS) ? lg[t] : -1e300;
    double vm = wave_max(x);
    if (l == 0) redw[w] = vm;
    __syncthreads();
    double mx = fmax(fmax(redw[0], redw[1]), fmax(redw[2], redw[3]));
    double e = (t < SS) ? exp(x - mx) : 0.0;
    double vs = wave_sum(e);
    __syncthreads();               // redw consumed by all before rewrite
    if (l == 0) redw[w] = vs;
    __syncthreads();
    double sum = redw[0] + redw[1] + redw[2] + redw[3];
    if (t < SS) lg[t] = e / sum;
  }
  __syncthreads();

  // ---- weighted sum of enc -> glimpse q (into hq), 4-way ILP ----
  {
    const float* eb = enc_c + (size_t)r * SS * HH + t;
    double acc0 = 0.0, acc1 = 0.0, acc2 = 0.0, acc3 = 0.0;
    for (int s = 0; s < SS; s += 4) {
      acc0 = fma((double)eb[(s + 0) * HH], lg[s + 0], acc0);
      acc1 = fma((double)eb[(s + 1) * HH], lg[s + 1], acc1);
      acc2 = fma((double)eb[(s + 2) * HH], lg[s + 2], acc2);
      acc3 = fma((double)eb[(s + 3) * HH], lg[s + 3], acc3);
    }
    hq[t] = (acc0 + acc1) + (acc2 + acc3);
  }
  __syncthreads();

  // ---- pointer query projection (fp64 accum, 4-way ILP) ----
  {
    double a0 = 0.0, a1 = 0.0, a2 = 0.0, a3 = 0.0;
    for (int k = 0; k < HH; k += 4) {
      a0 = fma((double)wqt_p[(k + 0) * HH + t], hq[k + 0], a0);
      a1 = fma((double)wqt_p[(k + 1) * HH + t], hq[k + 1], a1);
      a2 = fma((double)wqt_p[(k + 2) * HH + t], hq[k + 2], a2);
      a3 = fma((double)wqt_p[(k + 3) * HH + t], hq[k + 3], a3);
    }
    qvf[t] = (float)(((a0 + a1) + (a2 + a3)) + (double)bq_p[t]);
  }
  __syncthreads();

  // ---- pointer logits (fast fp32 tanh path) ----
  {
    const float4 vg = *(const float4*)(vw_p + l * 4);
    const float4 qf = *(const float4*)(qvf + l * 4);
    const float vb = vb_p[0];
    for (int s = w; s < SS; s += 4) {
      if (mask[r * SS + s]) {
        if (l == 0) lg[s] = -10.0;
        continue;
      }
      const float4 rp = *(const float4*)(ref_p + ((size_t)r * SS + s) * HH + l * 4);
      float p = tanh_fast(rp.x + qf.x) * vg.x;
      p = fmaf(tanh_fast(rp.y + qf.y), vg.y, p);
      p = fmaf(tanh_fast(rp.z + qf.z), vg.z, p);
      p = fmaf(tanh_fast(rp.w + qf.w), vg.w, p);
#pragma unroll
      for (int off = 32; off; off >>= 1) p += __shfl_xor(p, off);
      float z = 10.0f * tanh_fast(p + vb);
      if (l == 0) lg[s] = (double)z;
    }
  }
  __syncthreads();

  // ---- gumbel-argmax (partitionable threefry, exact round-3 recipe) ----
  // Kept in fp64: gumbel top-2 gaps can be small; fp32 here risks flips.
  double x = (t < SS) ? lg[t] : -1e300;
  double val = -1e300;
  int idx = t;
  if (t < SS) {
    unsigned kk0, kk1;
    threefry2x32(0u, 42u, 0u, (unsigned)step, kk0, kk1);
    unsigned j = (unsigned)(b * SS + t);
    unsigned o0, o1;
    threefry2x32(kk0, kk1, 0u, j, o0, o1);
    unsigned bits = o0 ^ o1;
    double u = (double)(bits >> 9) * 0x1p-23;
    if (u == 0.0) u = 1.17549435e-38;
    val = x + (-log(-log(u)));
  }
#pragma unroll
  for (int off = 32; off; off >>= 1) {
    double v2 = __shfl_xor(val, off);
    int i2 = __shfl_xor(idx, off);
    if (v2 > val || (v2 == val && i2 < idx)) { val = v2; idx = i2; }
  }
  if (l == 0) { redw[w] = val; ridxw[w] = idx; }
  __syncthreads();
  if (t == 0) {
    double bv = redw[0]; int bi = ridxw[0];
#pragma unroll
    for (int i = 1; i < 4; ++i) {
      if (redw[i] > bv || (redw[i] == bv && ridxw[i] < bi)) {
        bv = redw[i]; bi = ridxw[i];
      }
    }
    sh_chosen = bi;
  }
  __syncthreads();
  int chosen = sh_chosen;

  // ---- log-softmax pieces (fp64, wave reduce) ----
  {
    double vm = wave_max(x);
    if (l == 0) redw[w] = vm;
    __syncthreads();
    double mx = fmax(fmax(redw[0], redw[1]), fmax(redw[2], redw[3]));
    double e = (t < SS) ? exp(x - mx) : 0.0;
    double vs = wave_sum(e);
    __syncthreads();
    if (l == 0) redw[w] = vs;
    __syncthreads();
    if (t == 0) {
      double sum = redw[0] + redw[1] + redw[2] + redw[3];
      double lse = log(sum);
      double xc = lg[chosen];
      out[(size_t)b * SS + step] = (float)(xc - mx - lse);            // lps
      out[(size_t)BB * SS + (size_t)b * SS + step] = (float)chosen;   // chs
      mask[r * SS + chosen] = 1;
    }
  }

  // ---- dec_in = embedded[b, chosen, :] (fp64 recompute) ----
  int ib = (b * SS + chosen) * 2;
  double i0 = (double)inputs[ib], i1 = (double)inputs[ib + 1];
  dec_in[(size_t)r * HH + t] =
      i0 * (double)emb_w[2 * t] + i1 * (double)emb_w[2 * t + 1] + (double)emb_b[t];
}

// Diagnostic: encode ws_size (MB) into output so absmax reveals it.
__global__ __launch_bounds__(256) void diag_kernel(float* __restrict__ out, float v) {
  int i = blockIdx.x * 256 + threadIdx.x;
  if (i < 2 * BB * SS) out[i] = v;
}

// ---------------------------------------------------------------------------
extern "C" void kernel_launch(void* const* d_in, const int* in_sizes, int n_in,
                              void* d_out, int out_size, void* d_ws, size_t ws_size,
                              hipStream_t stream) {
  (void)in_sizes; (void)n_in; (void)out_size;
  const float* inputs    = (const float*)d_in[0];
  const float* emb_w     = (const float*)d_in[1];
  const float* emb_b     = (const float*)d_in[2];
  const float* enc_wih   = (const float*)d_in[3];
  const float* enc_whh   = (const float*)d_in[4];
  const float* enc_bih   = (const float*)d_in[5];
  const float* enc_bhh   = (const float*)d_in[6];
  const float* dec_wih   = (const float*)d_in[7];
  const float* dec_whh   = (const float*)d_in[8];
  const float* dec_bih   = (const float*)d_in[9];
  const float* dec_bhh   = (const float*)d_in[10];
  const float* ptr_wq_w  = (const float*)d_in[11];
  const float* ptr_wq_b  = (const float*)d_in[12];
  const float* ptr_wref_w= (const float*)d_in[13];
  const float* ptr_wref_b= (const float*)d_in[14];
  const float* ptr_v_w   = (const float*)d_in[15];
  const float* ptr_v_b   = (const float*)d_in[16];
  const float* glm_wq_w  = (const float*)d_in[17];
  const float* glm_wq_b  = (const float*)d_in[18];
  const float* glm_wref_w= (const float*)d_in[19];
  const float* glm_wref_b= (const float*)d_in[20];
  const float* glm_v_w   = (const float*)d_in[21];
  const float* glm_v_b   = (const float*)d_in[22];
  const float* start     = (const float*)d_in[23];
  float* out = (float*)d_out;

  // Runtime chunk selection: CH=1024 if workspace allows (1.6-2x parallelism
  // + half the serialized dispatches), else CH=512 (verified fit).
  auto bytes_needed = [](size_t chunk) -> size_t {
    auto al = [](size_t n) { return (n + 255) & ~(size_t)255; };
    size_t big = al(chunk * SS * HH * 4);
    return 3 * big + 3 * al(chunk * HH * 8) + al(chunk * SS * 4) +
           2 * al((size_t)HH * HH * 4);
  };
  size_t chunk = 1024;
  if (ws_size < bytes_needed(1024)) chunk = 512;
  if (ws_size < bytes_needed(512)) {
    diag_kernel<<<(2 * BB * SS + 255) / 256, 256, 0, stream>>>(
        out, (float)(ws_size >> 20));
    return;
  }

  char* base_p = (char*)d_ws;
  size_t off = 0;
  auto take = [&](size_t nbytes) {
    void* p = base_p + off;
    off = (off + nbytes + 255) & ~(size_t)255;
    return p;
  };
  const size_t BIGC = chunk * SS * HH;
  float*  enc_c  = (float*)take(BIGC * 4);
  float*  ref_g  = (float*)take(BIGC * 4);
  float*  ref_p  = (float*)take(BIGC * 4);
  double* hbuf   = (double*)take(chunk * HH * 8);
  double* cbuf   = (double*)take(chunk * HH * 8);
  double* dec_in = (double*)take(chunk * HH * 8);
  int*    mask   = (int*)take(chunk * SS * 4);
  float*  wqt_g  = (float*)take((size_t)HH * HH * 4);
  float*  wqt_p  = (float*)take((size_t)HH * HH * 4);

  transpose2<<<HH, HH, 0, stream>>>(glm_wq_w, ptr_wq_w, wqt_g, wqt_p);

  for (int cb = 0; cb < BB; cb += (int)chunk) {
    // ---- encoder ----
    init_chunk<<<(unsigned)chunk, 256, 0, stream>>>(hbuf, cbuf);
    for (int t = 0; t < SS; ++t) {
      lstm_gates<true><<<dim3((unsigned)chunk / 32, 16), 256, 0, stream>>>(
          inputs, emb_w, emb_b, t, cb, nullptr,
          enc_wih, enc_whh, enc_bih, enc_bhh, hbuf, cbuf, enc_c);
    }

    // ---- ref projections (chunk*SS rows) ----
    proj_gemm<<<dim3((unsigned)(chunk * SS / 64), 4), 256, 0, stream>>>(
        enc_c, glm_wref_w, glm_wref_b, ref_g);
    proj_gemm<<<dim3((unsigned)(chunk * SS / 64), 4), 256, 0, stream>>>(
        enc_c, ptr_wref_w, ptr_wref_b, ref_p);

    // ---- decoder ----
    init_dec<<<(unsigned)chunk, 256, 0, stream>>>(dec_in, mask, start);
    for (int k = 0; k < SS; ++k) {
      lstm_gates<false><<<dim3((unsigned)chunk / 32, 16), 256, 0, stream>>>(
          inputs, emb_w, emb_b, 0, cb, dec_in,
          dec_wih, dec_whh, dec_bih, dec_bhh, hbuf, cbuf, nullptr);
      dec_attn_sample<<<(unsigned)chunk, 256, 0, stream>>>(
          hbuf, enc_c, ref_g, ref_p,
          wqt_g, glm_wq_b, glm_v_w, glm_v_b,
          wqt_p, ptr_wq_b, ptr_v_w, ptr_v_b,
          mask, dec_in, inputs, emb_w, emb_b, out, k, cb);
    }
  }
}